// Round 1
// baseline (6245.435 us; speedup 1.0000x reference)
//
#include <hip/hip_runtime.h>
#include <math.h>

#define NN 65536
#define NE 1048576
#define NB 64
#define HD 128
#define NL 3

// ---- workspace layout (float offsets) ----
#define O_CSUM   0           // 64*3
#define O_CCNT   192         // 64
#define O_LCNT   256         // 64
#define O_GSUM   320         // 64*128
#define O_DEG    8512        // 65536
#define O_POSREL 74048       // 65536*3
#define O_DIST   270656      // 1048576
#define O_X      1319232     // 65536*128
#define O_P      9707840     // 65536*128
#define O_Q      18096448    // 65536*128
#define O_MSUM   26485056    // 65536*128  (end: 34873664 floats = 139.5 MB)

__device__ __forceinline__ void atomAdd(float* p, float v) {
    unsafeAtomicAdd(p, v);   // native global_atomic_add_f32 on gfx950
}

// ---------------- stats: per-graph centroid sums, node counts, ligand counts --------------
__global__ __launch_bounds__(256) void stats_kernel(
    const float* __restrict__ pos, const int* __restrict__ batch,
    const int* __restrict__ ntype,
    float* __restrict__ csum, float* __restrict__ ccnt, float* __restrict__ lcnt)
{
    __shared__ float s[NB * 5];
    const int tid = threadIdx.x;
    for (int i = tid; i < NB * 5; i += 256) s[i] = 0.f;
    __syncthreads();
    const int n = blockIdx.x * 256 + tid;
    const int b = batch[n];
    atomicAdd(&s[b*5+0], pos[n*3+0]);
    atomicAdd(&s[b*5+1], pos[n*3+1]);
    atomicAdd(&s[b*5+2], pos[n*3+2]);
    atomicAdd(&s[b*5+3], 1.f);
    if (ntype[n] == 1) atomicAdd(&s[b*5+4], 1.f);
    __syncthreads();
    for (int i = tid; i < NB * 5; i += 256) {
        float v = s[i];
        if (v != 0.f) {
            int b2 = i / 5, f = i - b2*5;
            if (f < 3)       atomAdd(&csum[b2*3+f], v);
            else if (f == 3) atomAdd(&ccnt[b2], v);
            else             atomAdd(&lcnt[b2], v);
        }
    }
}

// ---------------- degree of `row` endpoints (for segment mean) ----------------
__global__ __launch_bounds__(256) void deg_kernel(const int* __restrict__ row, float* __restrict__ deg)
{
    const int e = blockIdx.x * 256 + threadIdx.x;
    atomAdd(&deg[row[e]], 1.f);
}

// ---------------- pos_rel = pos - center[batch] ----------------
__global__ __launch_bounds__(256) void posrel_kernel(
    const float* __restrict__ pos, const int* __restrict__ batch,
    const float* __restrict__ csum, const float* __restrict__ ccnt,
    float* __restrict__ posrel)
{
    const int n = blockIdx.x * 256 + threadIdx.x;
    const int b = batch[n];
    const float inv = 1.f / fmaxf(ccnt[b], 1.f);
    posrel[n*3+0] = pos[n*3+0] - csum[b*3+0]*inv;
    posrel[n*3+1] = pos[n*3+1] - csum[b*3+1]*inv;
    posrel[n*3+2] = pos[n*3+2] - csum[b*3+2]*inv;
}

// ---------------- per-edge distance ----------------
__global__ __launch_bounds__(256) void dist_kernel(
    const float* __restrict__ posrel, const int* __restrict__ row,
    const int* __restrict__ col, float* __restrict__ dist)
{
    const int e = blockIdx.x * 256 + threadIdx.x;
    const int r = row[e], c = col[e];
    const float dx = posrel[c*3+0] - posrel[r*3+0];
    const float dy = posrel[c*3+1] - posrel[r*3+1];
    const float dz = posrel[c*3+2] - posrel[r*3+2];
    dist[e] = sqrtf(dx*dx + dy*dy + dz*dz);
}

// ---------------- generic node-level GEMM: out[N,128] = A[N,K] @ W[K,128] (+bias)(+relu) ----
// AMODE 0: A = concat(emb[z[n]], posrel[n])   (K=131)
// AMODE 1: A = x[n]                            (K=128)
// AMODE 2: A = concat(x[n], msum[n]/max(deg,1))(K=256)
template<int AMODE, int K, bool RELU>
__global__ __launch_bounds__(256) void node_gemm(
    const float* __restrict__ A0, const float* __restrict__ A1,
    const float* __restrict__ Adeg, const int* __restrict__ zidx,
    const float* __restrict__ W, const float* __restrict__ bias,
    float* __restrict__ out)
{
    constexpr int KP = (K % 4) ? (K + 4 - (K % 4)) : K;
    __shared__ __align__(16) float Asm[32][KP];
    __shared__ __align__(16) float Wsm[32][128];
    const int tid = threadIdx.x;
    const int n0  = blockIdx.x * 32;
    const float4* __restrict__ A0f4 = (const float4*)A0;

    if (AMODE == 0) {
        for (int idx4 = tid; idx4 < 1024; idx4 += 256) {
            int i = idx4 >> 5, k4 = idx4 & 31;
            int zz = zidx[n0 + i];
            *(float4*)&Asm[i][k4*4] = A0f4[zz*32 + k4];   // emb row
        }
        if (tid < 96) { int i = tid / 3, d = tid - i*3; Asm[i][128+d] = A1[(n0+i)*3 + d]; }
        else if (tid < 128) { Asm[tid-96][131] = 0.f; }
    } else if (AMODE == 1) {
        for (int idx4 = tid; idx4 < 1024; idx4 += 256) {
            int i = idx4 >> 5, k4 = idx4 & 31;
            *(float4*)&Asm[i][k4*4] = A0f4[(n0+i)*32 + k4];
        }
    } else {
        const float4* __restrict__ A1f4 = (const float4*)A1;
        for (int idx4 = tid; idx4 < 1024; idx4 += 256) {
            int i = idx4 >> 5, k4 = idx4 & 31;
            *(float4*)&Asm[i][k4*4] = A0f4[(n0+i)*32 + k4];
            float inv = 1.f / fmaxf(Adeg[n0+i], 1.f);
            float4 m = A1f4[(n0+i)*32 + k4];
            m.x *= inv; m.y *= inv; m.z *= inv; m.w *= inv;
            *(float4*)&Asm[i][128 + k4*4] = m;
        }
    }

    const int tj = tid & 31;   // col group: cols tj*4..tj*4+3
    const int tn = tid >> 5;   // node group: nodes tn*4..tn*4+3
    float acc[4][4];
    #pragma unroll
    for (int r = 0; r < 4; ++r)
        #pragma unroll
        for (int c = 0; c < 4; ++c) acc[r][c] = 0.f;

    const float4* __restrict__ Wf4 = (const float4*)W;
    #pragma unroll 1
    for (int kc = 0; kc < K; kc += 32) {
        const int kend = (K - kc < 32) ? (K - kc) : 32;
        __syncthreads();
        for (int idx4 = tid; idx4 < kend*32; idx4 += 256) {
            int kk = idx4 >> 5, j4 = idx4 & 31;
            *(float4*)&Wsm[kk][j4*4] = Wf4[(kc+kk)*32 + j4];
        }
        __syncthreads();
        for (int kk = 0; kk < kend; ++kk) {
            const float4 w = *(const float4*)&Wsm[kk][tj*4];
            const float a0 = Asm[tn*4+0][kc+kk];
            const float a1 = Asm[tn*4+1][kc+kk];
            const float a2 = Asm[tn*4+2][kc+kk];
            const float a3 = Asm[tn*4+3][kc+kk];
            acc[0][0] += a0*w.x; acc[0][1] += a0*w.y; acc[0][2] += a0*w.z; acc[0][3] += a0*w.w;
            acc[1][0] += a1*w.x; acc[1][1] += a1*w.y; acc[1][2] += a1*w.z; acc[1][3] += a1*w.w;
            acc[2][0] += a2*w.x; acc[2][1] += a2*w.y; acc[2][2] += a2*w.z; acc[2][3] += a2*w.w;
            acc[3][0] += a3*w.x; acc[3][1] += a3*w.y; acc[3][2] += a3*w.z; acc[3][3] += a3*w.w;
        }
    }

    float4 bias4 = make_float4(0.f, 0.f, 0.f, 0.f);
    if (bias) bias4 = ((const float4*)bias)[tj];
    #pragma unroll
    for (int r = 0; r < 4; ++r) {
        const int node = n0 + tn*4 + r;
        float4 o;
        o.x = acc[r][0] + bias4.x;
        o.y = acc[r][1] + bias4.y;
        o.z = acc[r][2] + bias4.z;
        o.w = acc[r][3] + bias4.w;
        if (RELU) {
            o.x = fmaxf(o.x, 0.f); o.y = fmaxf(o.y, 0.f);
            o.z = fmaxf(o.z, 0.f); o.w = fmaxf(o.w, 0.f);
        }
        ((float4*)out)[node*32 + tj] = o;
    }
}

// ---------------- fused edge kernel: h=relu(P[col]+Q[row]+dist*w1c+b1); m=relu(h@W2+b2);
// ----------------                    msum[row] += m  (segment-sum numerator) ----------------
__global__ __launch_bounds__(256) void edge_msg_kernel(
    const float* __restrict__ P, const float* __restrict__ Q,
    const float* __restrict__ dist, const int* __restrict__ row,
    const int* __restrict__ col,
    const float* __restrict__ w1c, const float* __restrict__ b1,
    const float* __restrict__ W2, const float* __restrict__ b2,
    float* __restrict__ msum)
{
    __shared__ __align__(16) float Hs[64][129];   // [edge][k], pad to kill bank conflicts
    __shared__ __align__(16) float W2s[32][128];
    __shared__ float c1s[HD], b1s[HD], b2s[HD];
    __shared__ int rows_s[64], cols_s[64];

    const int tid = threadIdx.x;
    const int e0  = blockIdx.x * 64;
    if (tid < HD) { c1s[tid] = w1c[tid]; b1s[tid] = b1[tid]; b2s[tid] = b2[tid]; }
    if (tid < 64) { rows_s[tid] = row[e0+tid]; cols_s[tid] = col[e0+tid]; }
    __syncthreads();

    // phase 1: H tile
    {
        const int j  = tid & 127;
        const int es = tid >> 7;          // 0..1
        #pragma unroll 4
        for (int i = 0; i < 32; ++i) {
            const int e = i*2 + es;
            const int c = cols_s[e], r = rows_s[e];
            float h = P[c*HD + j] + Q[r*HD + j] + dist[e0+e]*c1s[j] + b1s[j];
            Hs[e][j] = fmaxf(h, 0.f);
        }
    }
    __syncthreads();

    // phase 2: M[64,128] = Hs @ W2, thread tile = 8 edges x 4 cols
    const int cj = tid & 31;   // cols cj*4..+3
    const int eg = tid >> 5;   // edges eg*8..+7
    float acc[8][4];
    #pragma unroll
    for (int r = 0; r < 8; ++r)
        #pragma unroll
        for (int c = 0; c < 4; ++c) acc[r][c] = 0.f;

    #pragma unroll 1
    for (int kc = 0; kc < HD; kc += 32) {
        __syncthreads();
        for (int idx4 = tid; idx4 < 1024; idx4 += 256) {
            int kk = idx4 >> 5, j4 = idx4 & 31;
            *(float4*)&W2s[kk][j4*4] = ((const float4*)W2)[(kc+kk)*32 + j4];
        }
        __syncthreads();
        for (int kk = 0; kk < 32; ++kk) {
            const float4 w = *(const float4*)&W2s[kk][cj*4];
            float a[8];
            #pragma unroll
            for (int r = 0; r < 8; ++r) a[r] = Hs[eg*8+r][kc+kk];
            #pragma unroll
            for (int r = 0; r < 8; ++r) {
                acc[r][0] += a[r]*w.x; acc[r][1] += a[r]*w.y;
                acc[r][2] += a[r]*w.z; acc[r][3] += a[r]*w.w;
            }
        }
    }

    // phase 3: relu(+b2) and scatter-add into msum[row]
    const float4 b2v = *(const float4*)&b2s[cj*4];
    #pragma unroll
    for (int r = 0; r < 8; ++r) {
        const int e = eg*8 + r;
        const int base = rows_s[e]*HD + cj*4;
        atomAdd(&msum[base+0], fmaxf(acc[r][0] + b2v.x, 0.f));
        atomAdd(&msum[base+1], fmaxf(acc[r][1] + b2v.y, 0.f));
        atomAdd(&msum[base+2], fmaxf(acc[r][2] + b2v.z, 0.f));
        atomAdd(&msum[base+3], fmaxf(acc[r][3] + b2v.w, 0.f));
    }
}

// ---------------- ligand-masked per-graph sum of x ----------------
__global__ __launch_bounds__(256) void gsum_kernel(
    const float* __restrict__ x, const int* __restrict__ batch,
    const int* __restrict__ ntype, float* __restrict__ gsum)
{
    const int idx = blockIdx.x * 256 + threadIdx.x;
    const int n = idx >> 5, k4 = idx & 31;
    if (ntype[n] != 1) return;
    const int b = batch[n];
    const float4 v = ((const float4*)x)[n*32 + k4];
    float* dst = &gsum[b*HD + k4*4];
    atomAdd(dst+0, v.x); atomAdd(dst+1, v.y);
    atomAdd(dst+2, v.z); atomAdd(dst+3, v.w);
}

// ---------------- readout: hg = relu(g@ro_w1+b1); out = hg@ro_w2 + b2 ----------------
__global__ __launch_bounds__(128) void readout_kernel(
    const float* __restrict__ gsum, const float* __restrict__ lcnt,
    const float* __restrict__ w1, const float* __restrict__ b1,
    const float* __restrict__ w2, const float* __restrict__ b2,
    float* __restrict__ out)
{
    __shared__ float gs[HD];
    __shared__ float red[2];
    const int b = blockIdx.x, j = threadIdx.x;
    gs[j] = gsum[b*HD + j] / fmaxf(lcnt[b], 1.f);
    __syncthreads();
    float acc = b1[j];
    for (int k = 0; k < HD; ++k) acc += gs[k]*w1[k*HD + j];
    float hg = fmaxf(acc, 0.f) * w2[j];
    #pragma unroll
    for (int off = 32; off > 0; off >>= 1) hg += __shfl_down(hg, off, 64);
    if ((j & 63) == 0) red[j >> 6] = hg;
    __syncthreads();
    if (j == 0) out[b] = red[0] + red[1] + b2[0];
}

extern "C" void kernel_launch(void* const* d_in, const int* in_sizes, int n_in,
                              void* d_out, int out_size, void* d_ws, size_t ws_size,
                              hipStream_t stream)
{
    const float* pos   = (const float*)d_in[0];
    const int*   z     = (const int*)d_in[1];
    const int*   batch = (const int*)d_in[2];
    const int*   eidx  = (const int*)d_in[3];
    const int*   ntype = (const int*)d_in[4];
    const float* emb   = (const float*)d_in[5];
    const float* lin_w = (const float*)d_in[6];
    const float* lin_b = (const float*)d_in[7];
    const float* mw1   = (const float*)d_in[8];
    const float* mb1   = (const float*)d_in[9];
    const float* mw2   = (const float*)d_in[10];
    const float* mb2   = (const float*)d_in[11];
    const float* uw    = (const float*)d_in[12];
    const float* ub    = (const float*)d_in[13];
    const float* rw1   = (const float*)d_in[14];
    const float* rb1   = (const float*)d_in[15];
    const float* rw2   = (const float*)d_in[16];
    const float* rb2   = (const float*)d_in[17];

    const int* row = eidx;        // edge_index[0]
    const int* col = eidx + NE;   // edge_index[1]

    float* ws     = (float*)d_ws;
    float* csum   = ws + O_CSUM;
    float* ccnt   = ws + O_CCNT;
    float* lcnt   = ws + O_LCNT;
    float* gsum   = ws + O_GSUM;
    float* deg    = ws + O_DEG;
    float* posrel = ws + O_POSREL;
    float* dist   = ws + O_DIST;
    float* x      = ws + O_X;
    float* Pb     = ws + O_P;
    float* Qb     = ws + O_Q;
    float* msum   = ws + O_MSUM;

    // zero the stats block (csum..deg, includes gsum)
    hipMemsetAsync(ws, 0, (size_t)O_POSREL * sizeof(float), stream);

    stats_kernel <<<NN/256, 256, 0, stream>>>(pos, batch, ntype, csum, ccnt, lcnt);
    deg_kernel   <<<NE/256, 256, 0, stream>>>(row, deg);
    posrel_kernel<<<NN/256, 256, 0, stream>>>(pos, batch, csum, ccnt, posrel);
    dist_kernel  <<<NE/256, 256, 0, stream>>>(posrel, row, col, dist);

    // x = concat(emb[z], pos_rel) @ lin_in_w + b   (no relu)
    node_gemm<0, 131, false><<<NN/32, 256, 0, stream>>>(emb, posrel, nullptr, z, lin_w, lin_b, x);

    for (int l = 0; l < NL; ++l) {
        const float* W1 = mw1 + (size_t)l*257*HD;
        // P = x @ W1[0:128], Q = x @ W1[128:256]
        node_gemm<1, 128, false><<<NN/32, 256, 0, stream>>>(x, nullptr, nullptr, nullptr, W1, nullptr, Pb);
        node_gemm<1, 128, false><<<NN/32, 256, 0, stream>>>(x, nullptr, nullptr, nullptr, W1 + 128*HD, nullptr, Qb);
        hipMemsetAsync(msum, 0, (size_t)NN*HD*sizeof(float), stream);
        edge_msg_kernel<<<NE/64, 256, 0, stream>>>(Pb, Qb, dist, row, col,
                                                   W1 + 256*HD, mb1 + l*HD,
                                                   mw2 + (size_t)l*HD*HD, mb2 + l*HD, msum);
        // x = relu(concat(x, msum/deg) @ upd_w + b)   (in-place safe: block-local rows)
        node_gemm<2, 256, true><<<NN/32, 256, 0, stream>>>(x, msum, deg, nullptr,
                                                           uw + (size_t)l*256*HD, ub + l*HD, x);
    }

    gsum_kernel   <<<NN*32/256, 256, 0, stream>>>(x, batch, ntype, gsum);
    readout_kernel<<<NB, 128, 0, stream>>>(gsum, lcnt, rw1, rb1, rw2, rb2, (float*)d_out);
}

// Round 3
// 2429.848 us; speedup vs baseline: 2.5703x; 2.5703x over previous
//
#include <hip/hip_runtime.h>
#include <math.h>

#define NN 65536
#define NE 1048576
#define NB 64
#define HD 128
#define NL 3

// ---- workspace layout (float offsets) ----
#define O_CSUM   0           // 64*3
#define O_CCNT   192         // 64
#define O_LCNT   256         // 64
#define O_GSUM   320         // 64*128 -> ends 8512
#define O_DEGI   8512        // 65536 ints -> ends 74048
#define O_POSREL 74048       // 65536*3 -> ends 270656
#define O_RC     270656      // 1048576 u32 (row<<16|col, sorted by row) -> ends 1319232
#define O_X      1319232     // 65536*128  (rowStart/cnt alias its head pre-init)
#define O_P      9707840     // 65536*128
#define O_Q      18096448    // 65536*128
#define O_MSUM   26485056    // 65536*128  (end: 34873664 floats = 139.5 MB)

__device__ __forceinline__ void atomAdd(float* p, float v) {
    unsafeAtomicAdd(p, v);   // native global_atomic_add_f32 on gfx950
}

// ---------------- stats: per-graph centroid sums, node counts, ligand counts --------------
__global__ __launch_bounds__(256) void stats_kernel(
    const float* __restrict__ pos, const int* __restrict__ batch,
    const int* __restrict__ ntype,
    float* __restrict__ csum, float* __restrict__ ccnt, float* __restrict__ lcnt)
{
    __shared__ float s[NB * 5];
    const int tid = threadIdx.x;
    for (int i = tid; i < NB * 5; i += 256) s[i] = 0.f;
    __syncthreads();
    const int n = blockIdx.x * 256 + tid;
    const int b = batch[n];
    atomicAdd(&s[b*5+0], pos[n*3+0]);
    atomicAdd(&s[b*5+1], pos[n*3+1]);
    atomicAdd(&s[b*5+2], pos[n*3+2]);
    atomicAdd(&s[b*5+3], 1.f);
    if (ntype[n] == 1) atomicAdd(&s[b*5+4], 1.f);
    __syncthreads();
    for (int i = tid; i < NB * 5; i += 256) {
        float v = s[i];
        if (v != 0.f) {
            int b2 = i / 5, f = i - b2*5;
            if (f < 3)       atomAdd(&csum[b2*3+f], v);
            else if (f == 3) atomAdd(&ccnt[b2], v);
            else             atomAdd(&lcnt[b2], v);
        }
    }
}

// ---------------- integer degree histogram of `row` ----------------
__global__ __launch_bounds__(256) void deg_kernel(const int* __restrict__ row, int* __restrict__ degi)
{
    const int e = blockIdx.x * 256 + threadIdx.x;
    atomicAdd(&degi[row[e]], 1);
}

// ---------------- single-block exclusive scan of degi[65536] -> rowStart ----------------
__global__ __launch_bounds__(1024) void scan_kernel(const int* __restrict__ degi, int* __restrict__ rowStart)
{
    __shared__ int s[1024];
    __shared__ int carry;
    const int tid = threadIdx.x;
    if (tid == 0) carry = 0;
    __syncthreads();
    for (int c = 0; c < NN / 1024; ++c) {
        const int v = degi[c*1024 + tid];
        s[tid] = v;
        __syncthreads();
        for (int off = 1; off < 1024; off <<= 1) {
            int t = (tid >= off) ? s[tid - off] : 0;
            __syncthreads();
            s[tid] += t;
            __syncthreads();
        }
        rowStart[c*1024 + tid] = carry + s[tid] - v;   // exclusive
        __syncthreads();
        if (tid == 1023) carry += s[1023];
        __syncthreads();
    }
}

// ---------------- counting-sort scatter: rcS[p] = (row<<16)|col, sorted by row --------------
__global__ __launch_bounds__(256) void scatter_kernel(
    const int* __restrict__ row, const int* __restrict__ col,
    const int* __restrict__ rowStart, int* __restrict__ cnt,
    unsigned int* __restrict__ rcS)
{
    const int e = blockIdx.x * 256 + threadIdx.x;
    const int r = row[e], c = col[e];
    const int p = rowStart[r] + atomicAdd(&cnt[r], 1);
    rcS[p] = ((unsigned)r << 16) | (unsigned)c;
}

// ---------------- pos_rel = pos - center[batch] ----------------
__global__ __launch_bounds__(256) void posrel_kernel(
    const float* __restrict__ pos, const int* __restrict__ batch,
    const float* __restrict__ csum, const float* __restrict__ ccnt,
    float* __restrict__ posrel)
{
    const int n = blockIdx.x * 256 + threadIdx.x;
    const int b = batch[n];
    const float inv = 1.f / fmaxf(ccnt[b], 1.f);
    posrel[n*3+0] = pos[n*3+0] - csum[b*3+0]*inv;
    posrel[n*3+1] = pos[n*3+1] - csum[b*3+1]*inv;
    posrel[n*3+2] = pos[n*3+2] - csum[b*3+2]*inv;
}

// ---------------- generic node-level GEMM: out[N,128] = A[N,K] @ W[K,128] (+bias)(+relu) ----
// AMODE 0: A = concat(emb[z[n]], posrel[n])    (K=131)
// AMODE 1: A = x[n]                             (K=128)
// AMODE 2: A = concat(x[n], msum[n]/max(deg,1)) (K=256)
template<int AMODE, int K, bool RELU>
__global__ __launch_bounds__(256) void node_gemm(
    const float* __restrict__ A0, const float* __restrict__ A1,
    const int* __restrict__ Adeg, const int* __restrict__ zidx,
    const float* __restrict__ W, const float* __restrict__ bias,
    float* __restrict__ out)
{
    constexpr int KP = (K % 4) ? (K + 4 - (K % 4)) : K;
    __shared__ __align__(16) float Asm[32][KP];
    __shared__ __align__(16) float Wsm[32][128];
    const int tid = threadIdx.x;
    const int n0  = blockIdx.x * 32;
    const float4* __restrict__ A0f4 = (const float4*)A0;

    if constexpr (AMODE == 0) {
        for (int idx4 = tid; idx4 < 1024; idx4 += 256) {
            int i = idx4 >> 5, k4 = idx4 & 31;
            int zz = zidx[n0 + i];
            *(float4*)&Asm[i][k4*4] = A0f4[zz*32 + k4];   // emb row
        }
        if (tid < 96) { int i = tid / 3, d = tid - i*3; Asm[i][128+d] = A1[(n0+i)*3 + d]; }
        else if (tid < 128) { Asm[tid-96][131] = 0.f; }
    } else if constexpr (AMODE == 1) {
        for (int idx4 = tid; idx4 < 1024; idx4 += 256) {
            int i = idx4 >> 5, k4 = idx4 & 31;
            *(float4*)&Asm[i][k4*4] = A0f4[(n0+i)*32 + k4];
        }
    } else {
        const float4* __restrict__ A1f4 = (const float4*)A1;
        for (int idx4 = tid; idx4 < 1024; idx4 += 256) {
            int i = idx4 >> 5, k4 = idx4 & 31;
            *(float4*)&Asm[i][k4*4] = A0f4[(n0+i)*32 + k4];
            float inv = 1.f / fmaxf((float)Adeg[n0+i], 1.f);
            float4 m = A1f4[(n0+i)*32 + k4];
            m.x *= inv; m.y *= inv; m.z *= inv; m.w *= inv;
            *(float4*)&Asm[i][128 + k4*4] = m;
        }
    }

    const int tj = tid & 31;   // col group: cols tj*4..tj*4+3
    const int tn = tid >> 5;   // node group: nodes tn*4..tn*4+3
    float acc[4][4];
    #pragma unroll
    for (int r = 0; r < 4; ++r)
        #pragma unroll
        for (int c = 0; c < 4; ++c) acc[r][c] = 0.f;

    const float4* __restrict__ Wf4 = (const float4*)W;
    #pragma unroll 1
    for (int kc = 0; kc < K; kc += 32) {
        const int kend = (K - kc < 32) ? (K - kc) : 32;
        __syncthreads();
        for (int idx4 = tid; idx4 < kend*32; idx4 += 256) {
            int kk = idx4 >> 5, j4 = idx4 & 31;
            *(float4*)&Wsm[kk][j4*4] = Wf4[(kc+kk)*32 + j4];
        }
        __syncthreads();
        for (int kk = 0; kk < kend; ++kk) {
            const float4 w = *(const float4*)&Wsm[kk][tj*4];
            const float a0 = Asm[tn*4+0][kc+kk];
            const float a1 = Asm[tn*4+1][kc+kk];
            const float a2 = Asm[tn*4+2][kc+kk];
            const float a3 = Asm[tn*4+3][kc+kk];
            acc[0][0] += a0*w.x; acc[0][1] += a0*w.y; acc[0][2] += a0*w.z; acc[0][3] += a0*w.w;
            acc[1][0] += a1*w.x; acc[1][1] += a1*w.y; acc[1][2] += a1*w.z; acc[1][3] += a1*w.w;
            acc[2][0] += a2*w.x; acc[2][1] += a2*w.y; acc[2][2] += a2*w.z; acc[2][3] += a2*w.w;
            acc[3][0] += a3*w.x; acc[3][1] += a3*w.y; acc[3][2] += a3*w.z; acc[3][3] += a3*w.w;
        }
    }

    float4 bias4 = make_float4(0.f, 0.f, 0.f, 0.f);
    if (bias) bias4 = ((const float4*)bias)[tj];
    #pragma unroll
    for (int r = 0; r < 4; ++r) {
        const int node = n0 + tn*4 + r;
        float4 o;
        o.x = acc[r][0] + bias4.x;
        o.y = acc[r][1] + bias4.y;
        o.z = acc[r][2] + bias4.z;
        o.w = acc[r][3] + bias4.w;
        if (RELU) {
            o.x = fmaxf(o.x, 0.f); o.y = fmaxf(o.y, 0.f);
            o.z = fmaxf(o.z, 0.f); o.w = fmaxf(o.w, 0.f);
        }
        ((float4*)out)[node*32 + tj] = o;
    }
}

// ---------------- fused edge kernel over ROW-SORTED edges ----------------
// h = relu(P[col]+Q[row]+dist*w1c+b1); m = relu(h@W2+b2); msum[row] += m (run-aggregated)
__global__ __launch_bounds__(256) void edge_msg_kernel(
    const float* __restrict__ P, const float* __restrict__ Q,
    const float* __restrict__ posrel,
    const unsigned int* __restrict__ rcS,
    const float* __restrict__ w1c, const float* __restrict__ b1,
    const float* __restrict__ W2, const float* __restrict__ b2,
    float* __restrict__ msum)
{
    __shared__ __align__(16) float Hs[64][132];   // [edge][k], pad 132 (16B-aligned rows)
    __shared__ __align__(16) float W2s[32][128];
    __shared__ __align__(16) float c1s[HD], b1s[HD], b2s[HD];
    __shared__ __align__(16) float dists[64];
    __shared__ int rows_s[64], cols_s[64];

    const int tid = threadIdx.x;
    const long e0 = (long)blockIdx.x * 64;
    if (tid < HD) { c1s[tid] = w1c[tid]; b1s[tid] = b1[tid]; b2s[tid] = b2[tid]; }
    if (tid >= 128 && tid < 192) {
        const int e = tid - 128;
        const unsigned rc = rcS[e0 + e];
        const int r = (int)(rc >> 16), c = (int)(rc & 0xffffu);
        rows_s[e] = r; cols_s[e] = c;
        const float dx = posrel[c*3+0] - posrel[r*3+0];
        const float dy = posrel[c*3+1] - posrel[r*3+1];
        const float dz = posrel[c*3+2] - posrel[r*3+2];
        dists[e] = sqrtf(dx*dx + dy*dy + dz*dz);
    }
    __syncthreads();

    const int j4 = tid & 31;   // float4 column group
    const int eg = tid >> 5;   // 0..7, edges eg*8..eg*8+7

    // phase 1: H tile, float4 gathers (Q rows ~4-5 distinct per block -> L1 hits)
    {
        const float4 c14 = *(const float4*)&c1s[j4*4];
        const float4 b14 = *(const float4*)&b1s[j4*4];
        #pragma unroll
        for (int i = 0; i < 8; ++i) {
            const int e = eg*8 + i;
            const int c = cols_s[e], r = rows_s[e];
            const float4 p4 = ((const float4*)P)[c*32 + j4];
            const float4 q4 = ((const float4*)Q)[r*32 + j4];
            const float d = dists[e];
            float4 h;
            h.x = fmaxf(p4.x + q4.x + d*c14.x + b14.x, 0.f);
            h.y = fmaxf(p4.y + q4.y + d*c14.y + b14.y, 0.f);
            h.z = fmaxf(p4.z + q4.z + d*c14.z + b14.z, 0.f);
            h.w = fmaxf(p4.w + q4.w + d*c14.w + b14.w, 0.f);
            *(float4*)&Hs[e][j4*4] = h;
        }
    }

    // phase 2: M[64,128] = Hs @ W2, thread tile = 8 edges x 4 cols
    float acc[8][4];
    #pragma unroll
    for (int r = 0; r < 8; ++r)
        #pragma unroll
        for (int c = 0; c < 4; ++c) acc[r][c] = 0.f;

    #pragma unroll 1
    for (int kc = 0; kc < HD; kc += 32) {
        __syncthreads();
        for (int idx4 = tid; idx4 < 1024; idx4 += 256) {
            int kk = idx4 >> 5, jj = idx4 & 31;
            *(float4*)&W2s[kk][jj*4] = ((const float4*)W2)[(kc+kk)*32 + jj];
        }
        __syncthreads();
        for (int kk = 0; kk < 32; ++kk) {
            const float4 w = *(const float4*)&W2s[kk][j4*4];
            float a[8];
            #pragma unroll
            for (int r = 0; r < 8; ++r) a[r] = Hs[eg*8+r][kc+kk];
            #pragma unroll
            for (int r = 0; r < 8; ++r) {
                acc[r][0] += a[r]*w.x; acc[r][1] += a[r]*w.y;
                acc[r][2] += a[r]*w.z; acc[r][3] += a[r]*w.w;
            }
        }
    }

    // phase 3: relu(+b2), aggregate consecutive same-row results, then scatter-add
    const float4 b2v = *(const float4*)&b2s[j4*4];
    int curRow = -1;
    float4 run = make_float4(0.f, 0.f, 0.f, 0.f);
    #pragma unroll
    for (int r = 0; r < 8; ++r) {
        const int e = eg*8 + r;
        const int rw = rows_s[e];
        float4 m;
        m.x = fmaxf(acc[r][0] + b2v.x, 0.f);
        m.y = fmaxf(acc[r][1] + b2v.y, 0.f);
        m.z = fmaxf(acc[r][2] + b2v.z, 0.f);
        m.w = fmaxf(acc[r][3] + b2v.w, 0.f);
        if (rw != curRow) {
            if (curRow >= 0) {
                float* dst = &msum[(long)curRow*HD + j4*4];
                atomAdd(dst+0, run.x); atomAdd(dst+1, run.y);
                atomAdd(dst+2, run.z); atomAdd(dst+3, run.w);
            }
            curRow = rw; run = m;
        } else {
            run.x += m.x; run.y += m.y; run.z += m.z; run.w += m.w;
        }
    }
    {
        float* dst = &msum[(long)curRow*HD + j4*4];
        atomAdd(dst+0, run.x); atomAdd(dst+1, run.y);
        atomAdd(dst+2, run.z); atomAdd(dst+3, run.w);
    }
}

// ---------------- ligand-masked per-graph sum of x ----------------
__global__ __launch_bounds__(256) void gsum_kernel(
    const float* __restrict__ x, const int* __restrict__ batch,
    const int* __restrict__ ntype, float* __restrict__ gsum)
{
    const int idx = blockIdx.x * 256 + threadIdx.x;
    const int n = idx >> 5, k4 = idx & 31;
    if (ntype[n] != 1) return;
    const int b = batch[n];
    const float4 v = ((const float4*)x)[n*32 + k4];
    float* dst = &gsum[b*HD + k4*4];
    atomAdd(dst+0, v.x); atomAdd(dst+1, v.y);
    atomAdd(dst+2, v.z); atomAdd(dst+3, v.w);
}

// ---------------- readout: hg = relu(g@ro_w1+b1); out = hg@ro_w2 + b2 ----------------
__global__ __launch_bounds__(128) void readout_kernel(
    const float* __restrict__ gsum, const float* __restrict__ lcnt,
    const float* __restrict__ w1, const float* __restrict__ b1,
    const float* __restrict__ w2, const float* __restrict__ b2,
    float* __restrict__ out)
{
    __shared__ float gs[HD];
    __shared__ float red[2];
    const int b = blockIdx.x, j = threadIdx.x;
    gs[j] = gsum[b*HD + j] / fmaxf(lcnt[b], 1.f);
    __syncthreads();
    float acc = b1[j];
    for (int k = 0; k < HD; ++k) acc += gs[k]*w1[k*HD + j];
    float hg = fmaxf(acc, 0.f) * w2[j];
    #pragma unroll
    for (int off = 32; off > 0; off >>= 1) hg += __shfl_down(hg, off, 64);
    if ((j & 63) == 0) red[j >> 6] = hg;
    __syncthreads();
    if (j == 0) out[b] = red[0] + red[1] + b2[0];
}

extern "C" void kernel_launch(void* const* d_in, const int* in_sizes, int n_in,
                              void* d_out, int out_size, void* d_ws, size_t ws_size,
                              hipStream_t stream)
{
    const float* pos   = (const float*)d_in[0];
    const int*   z     = (const int*)d_in[1];
    const int*   batch = (const int*)d_in[2];
    const int*   eidx  = (const int*)d_in[3];
    const int*   ntype = (const int*)d_in[4];
    const float* emb   = (const float*)d_in[5];
    const float* lin_w = (const float*)d_in[6];
    const float* lin_b = (const float*)d_in[7];
    const float* mw1   = (const float*)d_in[8];
    const float* mb1   = (const float*)d_in[9];
    const float* mw2   = (const float*)d_in[10];
    const float* mb2   = (const float*)d_in[11];
    const float* uw    = (const float*)d_in[12];
    const float* ub    = (const float*)d_in[13];
    const float* rw1   = (const float*)d_in[14];
    const float* rb1   = (const float*)d_in[15];
    const float* rw2   = (const float*)d_in[16];
    const float* rb2   = (const float*)d_in[17];

    const int* row = eidx;        // edge_index[0]
    const int* col = eidx + NE;   // edge_index[1]

    float* ws     = (float*)d_ws;
    float* csum   = ws + O_CSUM;
    float* ccnt   = ws + O_CCNT;
    float* lcnt   = ws + O_LCNT;
    float* gsum   = ws + O_GSUM;
    int*   degi   = (int*)(ws + O_DEGI);
    float* posrel = ws + O_POSREL;
    unsigned int* rcS = (unsigned int*)(ws + O_RC);
    float* x      = ws + O_X;
    float* Pb     = ws + O_P;
    float* Qb     = ws + O_Q;
    float* msum   = ws + O_MSUM;
    // rowStart/cnt alias the head of x (x is written only after scatter completes)
    int* rowStart = (int*)x;
    int* cnt      = (int*)x + NN;

    // zero stats block (csum..gsum + degi) and cnt
    (void)hipMemsetAsync(ws, 0, (size_t)(O_DEGI + NN) * sizeof(float), stream);
    (void)hipMemsetAsync(cnt, 0, (size_t)NN * sizeof(int), stream);

    stats_kernel  <<<NN/256, 256, 0, stream>>>(pos, batch, ntype, csum, ccnt, lcnt);
    deg_kernel    <<<NE/256, 256, 0, stream>>>(row, degi);
    posrel_kernel <<<NN/256, 256, 0, stream>>>(pos, batch, csum, ccnt, posrel);
    scan_kernel   <<<1, 1024, 0, stream>>>(degi, rowStart);
    scatter_kernel<<<NE/256, 256, 0, stream>>>(row, col, rowStart, cnt, rcS);

    // x = concat(emb[z], pos_rel) @ lin_in_w + b   (no relu)
    node_gemm<0, 131, false><<<NN/32, 256, 0, stream>>>(emb, posrel, nullptr, z, lin_w, lin_b, x);

    for (int l = 0; l < NL; ++l) {
        const float* W1 = mw1 + (size_t)l*257*HD;
        // P = x @ W1[0:128], Q = x @ W1[128:256]
        node_gemm<1, 128, false><<<NN/32, 256, 0, stream>>>(x, nullptr, nullptr, nullptr, W1, nullptr, Pb);
        node_gemm<1, 128, false><<<NN/32, 256, 0, stream>>>(x, nullptr, nullptr, nullptr, W1 + 128*HD, nullptr, Qb);
        (void)hipMemsetAsync(msum, 0, (size_t)NN*HD*sizeof(float), stream);
        edge_msg_kernel<<<NE/64, 256, 0, stream>>>(Pb, Qb, posrel, rcS,
                                                   W1 + 256*HD, mb1 + l*HD,
                                                   mw2 + (size_t)l*HD*HD, mb2 + l*HD, msum);
        // x = relu(concat(x, msum/deg) @ upd_w + b)   (in-place safe: block-local rows)
        node_gemm<2, 256, true><<<NN/32, 256, 0, stream>>>(x, msum, degi, nullptr,
                                                           uw + (size_t)l*256*HD, ub + l*HD, x);
    }

    gsum_kernel   <<<NN*32/256, 256, 0, stream>>>(x, batch, ntype, gsum);
    readout_kernel<<<NB, 128, 0, stream>>>(gsum, lcnt, rw1, rb1, rw2, rb2, (float*)d_out);
}